// Round 5
// baseline (3858.567 us; speedup 1.0000x reference)
//
#include <hip/hip_runtime.h>
#include <hip/hip_bf16.h>
#include <math.h>

#define NN 100000
#define NE 640000
#define NB 2000

typedef __attribute__((ext_vector_type(8))) __bf16 v8bf;
typedef __attribute__((ext_vector_type(4))) float v4f;
#define MFMA(a, b, c) __builtin_amdgcn_mfma_f32_16x16x32_bf16(a, b, c, 0, 0, 0)

// ---------- int32/int64 index handling --------------------------------------
__device__ __forceinline__ int IDX(const void* p, size_t i, int is64) {
    return is64 ? (int)((const long long*)p)[i] : ((const int*)p)[i];
}
__device__ __forceinline__ int clampi(int v, int n) {
    return ((unsigned)v < (unsigned)n) ? v : 0;
}

__global__ void k_detect(const int* bn32, int* flag) {
    if (threadIdx.x == 0 && blockIdx.x == 0) {
        int is64 = 1;
        for (int k = 50001; k < 50401; k += 2)
            if (bn32[k] != 0) { is64 = 0; break; }
        *flag = is64;
    }
}

// ---------- bf16 helpers ----------------------------------------------------
__device__ __forceinline__ float bf_f(unsigned short u) {
    return __uint_as_float((unsigned)u << 16);
}
__device__ __forceinline__ unsigned short f_to_bf(float x) {
    __hip_bfloat16 h = __float2bfloat16(x);
    return *(unsigned short*)&h;
}

// ---------- fp8 e4m3 codec (denormals flushed) ------------------------------
__device__ __forceinline__ unsigned enc_fp8(float x) {
    unsigned s = (__float_as_uint(x) >> 24) & 0x80u;
    float ax = fminf(fabsf(x), 448.f);
    if (ax < 0.015625f) return s;
    unsigned b = __float_as_uint(ax) + 0x00080000u;
    unsigned e = (b >> 23) - 120u;
    unsigned m = (b >> 20) & 7u;
    return s | (e << 3) | m;
}
__device__ __forceinline__ float dec_fp8(unsigned b) {
    unsigned s = (b & 0x80u) << 24;
    unsigned e = (b >> 3) & 15u;
    unsigned m = b & 7u;
    float f = __uint_as_float(s | ((e + 120u) << 23) | (m << 20));
    return e ? f : 0.f;
}
__device__ __forceinline__ unsigned short dec8bf(unsigned b) {
    unsigned e = (b >> 3) & 15u, m = b & 7u, s = (b & 0x80u) << 8;
    return (unsigned short)(e ? (s | ((e + 120u) << 7) | (m << 4)) : s);
}

// ---------- node type embed -------------------------------------------------
__global__ __launch_bounds__(256) void k_node_embed(const float* __restrict__ h_node,
                                                    const float* __restrict__ W,
                                                    unsigned short* __restrict__ hn) {
    __shared__ float sh[8][16];
    int t = threadIdx.x;
    int r0 = blockIdx.x * 8;
    if (t < 128) sh[t >> 4][t & 15] = h_node[r0 * 16 + t];
    float w[16];
#pragma unroll
    for (int k = 0; k < 16; ++k) w[k] = W[k * 256 + t];
    __syncthreads();
#pragma unroll
    for (int r = 0; r < 8; ++r) {
        float acc = 0.f;
#pragma unroll
        for (int k = 0; k < 16; ++k) acc += sh[r][k] * w[k];
        hn[(size_t)(r0 + r) * 256 + t] = f_to_bf(acc);
    }
}

// ---------- edge type embed (fp8 out) ---------------------------------------
__global__ __launch_bounds__(256) void k_edge_embed(const float* __restrict__ h_edge,
                                                    const float* __restrict__ W,
                                                    unsigned char* __restrict__ he) {
    __shared__ float sh[16][5];
    int t = threadIdx.x;
    int e0 = blockIdx.x * 16;
    if (t < 80) sh[t / 5][t % 5] = h_edge[e0 * 5 + t];
    int c = t & 127;
    int es = t >> 7;
    float w[5];
#pragma unroll
    for (int k = 0; k < 5; ++k) w[k] = W[k * 128 + c];
    __syncthreads();
#pragma unroll
    for (int e = 0; e < 8; ++e) {
        int ee = es * 8 + e;
        float acc = 0.f;
#pragma unroll
        for (int k = 0; k < 5; ++k) acc += sh[ee][k] * w[k];
        he[(size_t)(e0 + ee) * 128 + c] = (unsigned char)enc_fp8(acc);
    }
}

// ---------- dist ------------------------------------------------------------
__global__ __launch_bounds__(256) void k_dist(const float* __restrict__ pos,
                                              const void* __restrict__ ei,
                                              const int* __restrict__ flag,
                                              float* __restrict__ dist) {
    int e = blockIdx.x * 256 + threadIdx.x;
    if (e >= NE) return;
    int is64 = *flag;
    int s = clampi(IDX(ei, e, is64), NN);
    int d = clampi(IDX(ei, (size_t)NE + e, is64), NN);
    float dx = pos[d * 3 + 0] - pos[s * 3 + 0];
    float dy = pos[d * 3 + 1] - pos[s * 3 + 1];
    float dz = pos[d * 3 + 2] - pos[s * 3 + 2];
    dist[e] = sqrtf(dx * dx + dy * dy + dz * dz);
}

// ---------- weight transposes to bf16 WT[N][K] ------------------------------
__global__ __launch_bounds__(256) void k_tr_eu(const float* __restrict__ W,
                                               unsigned short* __restrict__ WT) {
    int i = blockIdx.x * 256 + threadIdx.x;
    if (i >= 3 * 128 * 640) return;
    int l = i / (128 * 640), r = i % (128 * 640);
    int n = r / 640, k = r % 640;
    WT[i] = f_to_bf(W[(size_t)l * 641 * 128 + (size_t)k * 128 + n]);
}
__global__ __launch_bounds__(256) void k_tr_msg(const float* __restrict__ W,
                                                unsigned short* __restrict__ WT) {
    int i = blockIdx.x * 256 + threadIdx.x;
    if (i >= 3 * 256 * 384) return;
    int l = i / (256 * 384), r = i % (256 * 384);
    int n = r / 384, k = r % 384;
    WT[i] = f_to_bf(W[(size_t)l * 384 * 256 + (size_t)k * 256 + n]);
}
__global__ __launch_bounds__(256) void k_tr_nu(const float* __restrict__ W,
                                               unsigned short* __restrict__ WT) {
    int i = blockIdx.x * 256 + threadIdx.x;
    if (i >= 3 * 256 * 512) return;
    int l = i / (256 * 512), r = i % (256 * 512);
    int n = r / 512, k = r % 512;
    WT[i] = f_to_bf(W[(size_t)l * 512 * 256 + (size_t)k * 256 + n]);
}

// ---------- MFMA edge layer: 32 edges/block, 4 waves ------------------------
#define EL_LDSA 648  // 640 + 8 pad
#define EL_LDSH 136  // 128 + 8 pad

__global__ __launch_bounds__(256, 3) void k_edge_layer_mfma(
    const unsigned short* __restrict__ hn, unsigned char* __restrict__ he,
    const float* __restrict__ dist,
    const void* __restrict__ ei, const int* __restrict__ flag,
    const unsigned short* __restrict__ WTeu, const float* __restrict__ W_eu,
    const float* __restrict__ b_eu,
    const unsigned short* __restrict__ WTmsg, const float* __restrict__ b_msg,
    unsigned short* __restrict__ agg) {
    __shared__ unsigned short s_A[32 * EL_LDSA];
    __shared__ unsigned short s_h[32 * EL_LDSH];
    __shared__ float s_dist[32];
    __shared__ int s_dsti[32];
    int t = threadIdx.x;
    int eb = blockIdx.x * 32;
    int is64 = *flag;

    if (t < 32) {
        s_dsti[t] = clampi(IDX(ei, (size_t)NE + eb + t, is64), NN);
        s_dist[t] = dist[eb + t];
    }
    // stage he fp8 -> bf16, k 0..127
    {
        int e = t >> 3, c = (t & 7) * 16;
        uint4 q = *(const uint4*)(he + (size_t)(eb + e) * 128 + c);
        unsigned short* d = &s_A[e * EL_LDSA + c];
        unsigned v[4] = {q.x, q.y, q.z, q.w};
#pragma unroll
        for (int j = 0; j < 4; ++j)
#pragma unroll
            for (int b = 0; b < 4; ++b)
                d[j * 4 + b] = dec8bf((v[j] >> (8 * b)) & 255u);
    }
    // stage hn[src] -> k 128..383
    {
        int e = t >> 3, c = (t & 7) * 32;
        int id = clampi(IDX(ei, (size_t)eb + e, is64), NN);
        const unsigned short* sp = hn + (size_t)id * 256 + c;
        unsigned short* d = &s_A[e * EL_LDSA + 128 + c];
#pragma unroll
        for (int j = 0; j < 4; ++j)
            *(uint4*)&d[j * 8] = *(const uint4*)&sp[j * 8];
    }
    // stage hn[dst] -> k 384..639
    {
        int e = t >> 3, c = (t & 7) * 32;
        int id = clampi(IDX(ei, (size_t)NE + eb + e, is64), NN);
        const unsigned short* sp = hn + (size_t)id * 256 + c;
        unsigned short* d = &s_A[e * EL_LDSA + 384 + c];
#pragma unroll
        for (int j = 0; j < 4; ++j)
            *(uint4*)&d[j * 8] = *(const uint4*)&sp[j * 8];
    }
    __syncthreads();

    int lane = t & 63, wv = t >> 6;
    int quad = lane >> 4, l16 = lane & 15;

    // ---- edge update GEMM: wave -> ntiles {2w,2w+1}, mtiles {0,1} ----
    v4f zero4 = {0.f, 0.f, 0.f, 0.f};
    v4f acc[2][2];
    acc[0][0] = zero4; acc[0][1] = zero4; acc[1][0] = zero4; acc[1][1] = zero4;
    const unsigned short* A0 = &s_A[l16 * EL_LDSA];
    const unsigned short* A1 = &s_A[(16 + l16) * EL_LDSA];
    int n0 = wv * 2;
    const unsigned short* B0 = &WTeu[(size_t)(n0 * 16 + l16) * 640];
    const unsigned short* B1 = &WTeu[(size_t)((n0 + 1) * 16 + l16) * 640];
#pragma unroll
    for (int k = 0; k < 640; k += 32) {
        int ko = k + quad * 8;
        v8bf a0 = *(const v8bf*)&A0[ko];
        v8bf a1 = *(const v8bf*)&A1[ko];
        v8bf b0 = *(const v8bf*)&B0[ko];
        v8bf b1 = *(const v8bf*)&B1[ko];
        acc[0][0] = MFMA(a0, b0, acc[0][0]);
        acc[1][0] = MFMA(a1, b0, acc[1][0]);
        acc[0][1] = MFMA(a0, b1, acc[0][1]);
        acc[1][1] = MFMA(a1, b1, acc[1][1]);
    }

    // ---- msg GEMM part A (K=0..255 over hn_src region, independent of s_h) --
    v4f mac[2][4];
#pragma unroll
    for (int nl = 0; nl < 4; ++nl) { mac[0][nl] = zero4; mac[1][nl] = zero4; }
    const unsigned short* MA0 = &s_A[l16 * EL_LDSA + 128];
    const unsigned short* MA1 = &s_A[(16 + l16) * EL_LDSA + 128];
    int q0 = wv * 4;
    const unsigned short* MB[4];
#pragma unroll
    for (int nl = 0; nl < 4; ++nl)
        MB[nl] = &WTmsg[(size_t)((q0 + nl) * 16 + l16) * 384];
#pragma unroll
    for (int k = 0; k < 256; k += 32) {
        int ko = k + quad * 8;
        v8bf a0 = *(const v8bf*)&MA0[ko];
        v8bf a1 = *(const v8bf*)&MA1[ko];
#pragma unroll
        for (int nl = 0; nl < 4; ++nl) {
            v8bf b = *(const v8bf*)&MB[nl][ko];
            mac[0][nl] = MFMA(a0, b, mac[0][nl]);
            mac[1][nl] = MFMA(a1, b, mac[1][nl]);
        }
    }

    // ---- edge epilogue: + dist*w640 + bias, relu -> s_h (bf16) + he (fp8) ---
#pragma unroll
    for (int nl = 0; nl < 2; ++nl) {
        int c = (n0 + nl) * 16 + l16;
        float w640 = W_eu[640 * 128 + c];
        float bb = b_eu[c];
#pragma unroll
        for (int mt = 0; mt < 2; ++mt)
#pragma unroll
            for (int r = 0; r < 4; ++r) {
                int row = mt * 16 + quad * 4 + r;
                float v = acc[mt][nl][r] + s_dist[row] * w640 + bb;
                v = fmaxf(v, 0.f);
                s_h[row * EL_LDSH + c] = f_to_bf(v);
                he[(size_t)(eb + row) * 128 + c] = (unsigned char)enc_fp8(v);
            }
    }
    __syncthreads();

    // ---- msg GEMM part B (K=128 over he_new from s_h) ----
    const unsigned short* HA0 = &s_h[l16 * EL_LDSH];
    const unsigned short* HA1 = &s_h[(16 + l16) * EL_LDSH];
#pragma unroll
    for (int k = 0; k < 128; k += 32) {
        int ko = k + quad * 8;
        v8bf a0 = *(const v8bf*)&HA0[ko];
        v8bf a1 = *(const v8bf*)&HA1[ko];
#pragma unroll
        for (int nl = 0; nl < 4; ++nl) {
            v8bf b = *(const v8bf*)&MB[nl][256 + ko];
            mac[0][nl] = MFMA(a0, b, mac[0][nl]);
            mac[1][nl] = MFMA(a1, b, mac[1][nl]);
        }
    }

    // ---- epilogue: bias + relu + packed bf16 scatter atomics ----
#pragma unroll
    for (int nl = 0; nl < 4; ++nl) {
        int c = (q0 + nl) * 16 + l16;
        float bm = b_msg[c];
        int cb = c & ~1;
#pragma unroll
        for (int mt = 0; mt < 2; ++mt)
#pragma unroll
            for (int r = 0; r < 4; ++r) {
                int row = mt * 16 + quad * 4 + r;
                float v = fmaxf(mac[mt][nl][r] + bm, 0.f);
                float w = __shfl_xor(v, 1, 64);  // neighbor column's value
                // even l16 issues r 0,1; odd l16 issues r 2,3
                if (((l16 ^ (r >> 1)) & 1) == 0) {
                    __hip_bfloat162 p;
                    if (l16 & 1) {
                        p.x = __float2bfloat16(w);
                        p.y = __float2bfloat16(v);
                    } else {
                        p.x = __float2bfloat16(v);
                        p.y = __float2bfloat16(w);
                    }
                    unsafeAtomicAdd(
                        (__hip_bfloat162*)&agg[(size_t)s_dsti[row] * 256 + cb], p);
                }
            }
    }
}

// ---------- MFMA node layer: 32 nodes/block ---------------------------------
#define NL_LDSA 520  // 512 + 8 pad

__global__ __launch_bounds__(256, 3) void k_node_layer_mfma(
    unsigned short* __restrict__ hn, const unsigned short* __restrict__ agg,
    const unsigned short* __restrict__ WTnu, const float* __restrict__ b) {
    __shared__ unsigned short s_A[32 * NL_LDSA];
    int t = threadIdx.x;
    int rb = blockIdx.x * 32;
    // stage hn bf16 (k 0..255)
    {
        int e = t >> 3, c = (t & 7) * 32;
        const unsigned short* sp = hn + (size_t)(rb + e) * 256 + c;
        unsigned short* d = &s_A[e * NL_LDSA + c];
#pragma unroll
        for (int j = 0; j < 4; ++j)
            *(uint4*)&d[j * 8] = *(const uint4*)&sp[j * 8];
    }
    // stage agg bf16 (k 256..511)
    {
        int e = t >> 3, c = (t & 7) * 32;
        const unsigned short* sp = agg + (size_t)(rb + e) * 256 + c;
        unsigned short* d = &s_A[e * NL_LDSA + 256 + c];
#pragma unroll
        for (int j = 0; j < 4; ++j)
            *(uint4*)&d[j * 8] = *(const uint4*)&sp[j * 8];
    }
    __syncthreads();
    int lane = t & 63, wv = t >> 6, quad = lane >> 4, l16 = lane & 15;
    v4f zero4 = {0.f, 0.f, 0.f, 0.f};
    v4f acc[2][4];
#pragma unroll
    for (int nl = 0; nl < 4; ++nl) { acc[0][nl] = zero4; acc[1][nl] = zero4; }
    const unsigned short* A0 = &s_A[l16 * NL_LDSA];
    const unsigned short* A1 = &s_A[(16 + l16) * NL_LDSA];
    int q0 = wv * 4;
#pragma unroll
    for (int k = 0; k < 512; k += 32) {
        int ko = k + quad * 8;
        v8bf a0 = *(const v8bf*)&A0[ko];
        v8bf a1 = *(const v8bf*)&A1[ko];
#pragma unroll
        for (int nl = 0; nl < 4; ++nl) {
            v8bf bb = *(const v8bf*)&WTnu[(size_t)((q0 + nl) * 16 + l16) * 512 + ko];
            acc[0][nl] = MFMA(a0, bb, acc[0][nl]);
            acc[1][nl] = MFMA(a1, bb, acc[1][nl]);
        }
    }
#pragma unroll
    for (int nl = 0; nl < 4; ++nl) {
        int c = (q0 + nl) * 16 + l16;
        float bv = b[c];
#pragma unroll
        for (int mt = 0; mt < 2; ++mt)
#pragma unroll
            for (int r = 0; r < 4; ++r) {
                int row = mt * 16 + quad * 4 + r;
                float old = bf_f(s_A[row * NL_LDSA + c]);
                float v = old + fmaxf(acc[mt][nl][r] + bv, 0.f);
                hn[(size_t)(rb + row) * 256 + c] = f_to_bf(v);
            }
    }
}

// ---------- pooling + final MLP --------------------------------------------
__device__ __forceinline__ int lbound(const void* a, int n, int v, int is64) {
    int lo = 0, hi = n;
    while (lo < hi) {
        int mid = (lo + hi) >> 1;
        if (IDX(a, mid, is64) < v) lo = mid + 1; else hi = mid;
    }
    return lo;
}

__global__ __launch_bounds__(512) void k_pool_mlp(
    const unsigned short* __restrict__ hn, const unsigned char* __restrict__ he,
    const void* __restrict__ bn, const void* __restrict__ be,
    const int* __restrict__ flag,
    const float* __restrict__ Wf1, const float* __restrict__ bf1,
    const float* __restrict__ Wf2, const float* __restrict__ bf2,
    float* __restrict__ out) {
    __shared__ float s_sub[384];
    __shared__ float s_hid[512];
    int b = blockIdx.x;
    int t = threadIdx.x;
    int is64 = *flag;
    if (t < 256) {
        int lo = lbound(bn, NN, b, is64), hi = lbound(bn, NN, b + 1, is64);
        float s = 0.f;
        for (int i = lo; i < hi; ++i) s += bf_f(hn[(size_t)i * 256 + t]);
        s_sub[t] = s / fmaxf((float)(hi - lo), 1.f);
    } else if (t < 384) {
        int c = t - 256;
        int lo = lbound(be, NE, b, is64), hi = lbound(be, NE, b + 1, is64);
        float s = 0.f;
        for (int i = lo; i < hi; ++i) s += dec_fp8(he[(size_t)i * 128 + c]);
        s_sub[256 + c] = s / fmaxf((float)(hi - lo), 1.f);
    }
    __syncthreads();
    float hacc = bf1[t];
    for (int k = 0; k < 384; ++k) hacc += s_sub[k] * Wf1[k * 512 + t];
    s_hid[t] = fmaxf(hacc, 0.f);
    __syncthreads();
    if (t < 256) {
        float o = bf2[t];
        for (int k = 0; k < 512; ++k) o += s_hid[k] * Wf2[k * 256 + t];
        out[(size_t)b * 256 + t] = o;
    }
}

// ---------- second output ---------------------------------------------------
__global__ __launch_bounds__(256) void k_write_batch(const void* __restrict__ bn,
                                                     const int* __restrict__ flag,
                                                     float* __restrict__ out) {
    int i = blockIdx.x * 256 + threadIdx.x;
    if (i < NN) out[(size_t)NB * 256 + i] = (float)IDX(bn, i, *flag);
}

__global__ __launch_bounds__(256) void k_fill(float* __restrict__ p, int n, float v) {
    int i = blockIdx.x * 256 + threadIdx.x;
    if (i < n) p[i] = v;
}

extern "C" void kernel_launch(void* const* d_in, const int* in_sizes, int n_in,
                              void* d_out, int out_size, void* d_ws, size_t ws_size,
                              hipStream_t stream) {
    const float* h_node = (const float*)d_in[0];
    const float* pos    = (const float*)d_in[1];
    const float* h_edge = (const float*)d_in[2];
    const float* W_node = (const float*)d_in[3];
    const float* W_edge = (const float*)d_in[4];
    const float* W_eu   = (const float*)d_in[5];
    const float* b_eu   = (const float*)d_in[6];
    const float* W_msg  = (const float*)d_in[7];
    const float* b_msg  = (const float*)d_in[8];
    const float* W_nu   = (const float*)d_in[9];
    const float* b_nu   = (const float*)d_in[10];
    const float* Wf1    = (const float*)d_in[11];
    const float* bf1    = (const float*)d_in[12];
    const float* Wf2    = (const float*)d_in[13];
    const float* bf2    = (const float*)d_in[14];
    const void* ei = d_in[15];
    const void* bn = d_in[16];
    const void* be = d_in[17];

    float* out = (float*)d_out;

    const size_t SZ_FLAG  = 256;
    const size_t SZ_HN    = (size_t)NN * 256 * 2;       //  51.2  MB (bf16)
    const size_t SZ_HE    = (size_t)NE * 128 * 1;       //  81.92 MB (fp8)
    const size_t SZ_AGG   = (size_t)NN * 256 * 2;       //  51.2  MB (bf16)
    const size_t SZ_DIST  = (size_t)NE * 4;             //   2.56 MB
    const size_t SZ_WTEU  = (size_t)3 * 128 * 640 * 2;
    const size_t SZ_WTMSG = (size_t)3 * 256 * 384 * 2;
    const size_t SZ_WTNU  = (size_t)3 * 256 * 512 * 2;
    const size_t NEED = SZ_FLAG + SZ_HN + SZ_HE + SZ_AGG + SZ_DIST +
                        SZ_WTEU + SZ_WTMSG + SZ_WTNU;   // ~189 MB

    char* ws = (char*)d_ws;
    int* flag = (int*)ws;                          ws += SZ_FLAG;
    unsigned short* hn = (unsigned short*)ws;      ws += SZ_HN;
    unsigned char* he = (unsigned char*)ws;        ws += SZ_HE;
    unsigned short* agg = (unsigned short*)ws;     ws += SZ_AGG;
    float* dist = (float*)ws;                      ws += SZ_DIST;
    unsigned short* WTeu = (unsigned short*)ws;    ws += SZ_WTEU;
    unsigned short* WTmsg = (unsigned short*)ws;   ws += SZ_WTMSG;
    unsigned short* WTnu = (unsigned short*)ws;    ws += SZ_WTNU;

    if (ws_size < NEED) {
        float enc = -(100000.0f + (float)(ws_size >> 20));
        k_detect<<<1, 64, 0, stream>>>((const int*)bn, flag);
        k_fill<<<(NB * 256 + 255) / 256, 256, 0, stream>>>(out, NB * 256, enc);
        k_write_batch<<<(NN + 255) / 256, 256, 0, stream>>>(bn, flag, out);
        return;
    }

    k_detect<<<1, 64, 0, stream>>>((const int*)bn, flag);
    k_tr_eu<<<(3 * 128 * 640 + 255) / 256, 256, 0, stream>>>(W_eu, WTeu);
    k_tr_msg<<<(3 * 256 * 384 + 255) / 256, 256, 0, stream>>>(W_msg, WTmsg);
    k_tr_nu<<<(3 * 256 * 512 + 255) / 256, 256, 0, stream>>>(W_nu, WTnu);
    k_node_embed<<<NN / 8, 256, 0, stream>>>(h_node, W_node, hn);
    k_edge_embed<<<NE / 16, 256, 0, stream>>>(h_edge, W_edge, he);
    k_dist<<<(NE + 255) / 256, 256, 0, stream>>>(pos, ei, flag, dist);

    for (int l = 0; l < 3; ++l) {
        hipMemsetAsync(agg, 0, SZ_AGG, stream);
        k_edge_layer_mfma<<<NE / 32, 256, 0, stream>>>(
            hn, he, dist, ei, flag,
            WTeu + (size_t)l * 128 * 640, W_eu + (size_t)l * 641 * 128,
            b_eu + (size_t)l * 128,
            WTmsg + (size_t)l * 256 * 384, b_msg + (size_t)l * 256, agg);
        k_node_layer_mfma<<<NN / 32, 256, 0, stream>>>(
            hn, agg, WTnu + (size_t)l * 256 * 512, b_nu + (size_t)l * 256);
    }

    k_pool_mlp<<<NB, 512, 0, stream>>>(hn, he, bn, be, flag,
                                       Wf1, bf1, Wf2, bf2, out);
    k_write_batch<<<(NN + 255) / 256, 256, 0, stream>>>(bn, flag, out);
}

// Round 6
// 2947.804 us; speedup vs baseline: 1.3090x; 1.3090x over previous
//
#include <hip/hip_runtime.h>
#include <hip/hip_bf16.h>
#include <math.h>

#define NN 100000
#define NE 640000
#define NB 2000

typedef __attribute__((ext_vector_type(4))) float v4f;
typedef long long ll64;
#define MFMA8(a, b, c) __builtin_amdgcn_mfma_f32_16x16x32_fp8_fp8(a, b, c, 0, 0, 0)

// scales: activations x16, weights x256, accum de-scale 1/4096
#define INV_S 0.000244140625f
#define ASCL 16.0f
#define AINV 0.0625f

// ---------- int32/int64 index handling --------------------------------------
__device__ __forceinline__ int IDX(const void* p, size_t i, int is64) {
    return is64 ? (int)((const long long*)p)[i] : ((const int*)p)[i];
}
__device__ __forceinline__ int clampi(int v, int n) {
    return ((unsigned)v < (unsigned)n) ? v : 0;
}

__global__ void k_detect(const int* bn32, int* flag) {
    if (threadIdx.x == 0 && blockIdx.x == 0) {
        int is64 = 1;
        for (int k = 50001; k < 50401; k += 2)
            if (bn32[k] != 0) { is64 = 0; break; }
        *flag = is64;
    }
}

// ---------- fp8 e4m3 codec (with denormals) ---------------------------------
__device__ __forceinline__ unsigned enc_fp8(float x) {
    unsigned s = (__float_as_uint(x) >> 24) & 0x80u;
    float ax = fminf(fabsf(x), 448.f);
    if (ax < 0.015625f) {
        unsigned m = (unsigned)(ax * 512.f + 0.5f);  // 0..8 (8 rolls to e=1,m=0)
        return s | m;
    }
    unsigned b = __float_as_uint(ax) + 0x00080000u;
    unsigned e = (b >> 23) - 120u;
    unsigned m = (b >> 20) & 7u;
    unsigned v = (e << 3) | m;
    if (v > 0x7Eu) v = 0x7Eu;  // never emit NaN pattern
    return s | v;
}
__device__ __forceinline__ float dec_fp8(unsigned b) {
    unsigned s = (b & 0x80u) << 24;
    unsigned e = (b >> 3) & 15u;
    unsigned m = b & 7u;
    if (e) return __uint_as_float(s | ((e + 120u) << 23) | (m << 20));
    float f = (float)m * 0.001953125f;
    return (b & 0x80u) ? -f : f;
}

// ---------- node type embed: hn8 = enc(16 * h_node @ W_node) ----------------
__global__ __launch_bounds__(256) void k_node_embed(const float* __restrict__ h_node,
                                                    const float* __restrict__ W,
                                                    unsigned char* __restrict__ hn8) {
    __shared__ float sh[8][16];
    int t = threadIdx.x;
    int r0 = blockIdx.x * 8;
    if (t < 128) sh[t >> 4][t & 15] = h_node[r0 * 16 + t];
    float w[16];
#pragma unroll
    for (int k = 0; k < 16; ++k) w[k] = W[k * 256 + t];
    __syncthreads();
#pragma unroll
    for (int r = 0; r < 8; ++r) {
        float acc = 0.f;
#pragma unroll
        for (int k = 0; k < 16; ++k) acc += sh[r][k] * w[k];
        hn8[(size_t)(r0 + r) * 256 + t] = (unsigned char)enc_fp8(ASCL * acc);
    }
}

// ---------- edge type embed: he8 = enc(16 * h_edge @ W_edge) ----------------
__global__ __launch_bounds__(256) void k_edge_embed(const float* __restrict__ h_edge,
                                                    const float* __restrict__ W,
                                                    unsigned char* __restrict__ he8) {
    __shared__ float sh[16][5];
    int t = threadIdx.x;
    int e0 = blockIdx.x * 16;
    if (t < 80) sh[t / 5][t % 5] = h_edge[e0 * 5 + t];
    int c = t & 127;
    int es = t >> 7;
    float w[5];
#pragma unroll
    for (int k = 0; k < 5; ++k) w[k] = W[k * 128 + c];
    __syncthreads();
#pragma unroll
    for (int e = 0; e < 8; ++e) {
        int ee = es * 8 + e;
        float acc = 0.f;
#pragma unroll
        for (int k = 0; k < 5; ++k) acc += sh[ee][k] * w[k];
        he8[(size_t)(e0 + ee) * 128 + c] = (unsigned char)enc_fp8(ASCL * acc);
    }
}

// ---------- dist ------------------------------------------------------------
__global__ __launch_bounds__(256) void k_dist(const float* __restrict__ pos,
                                              const void* __restrict__ ei,
                                              const int* __restrict__ flag,
                                              float* __restrict__ dist) {
    int e = blockIdx.x * 256 + threadIdx.x;
    if (e >= NE) return;
    int is64 = *flag;
    int s = clampi(IDX(ei, e, is64), NN);
    int d = clampi(IDX(ei, (size_t)NE + e, is64), NN);
    float dx = pos[d * 3 + 0] - pos[s * 3 + 0];
    float dy = pos[d * 3 + 1] - pos[s * 3 + 1];
    float dz = pos[d * 3 + 2] - pos[s * 3 + 2];
    dist[e] = sqrtf(dx * dx + dy * dy + dz * dz);
}

// ---------- weight transposes to fp8 WT[N][K], scaled x256 ------------------
__global__ __launch_bounds__(256) void k_tr_eu(const float* __restrict__ W,
                                               unsigned char* __restrict__ WT) {
    int i = blockIdx.x * 256 + threadIdx.x;
    if (i >= 3 * 128 * 640) return;
    int l = i / (128 * 640), r = i % (128 * 640);
    int n = r / 640, k = r % 640;
    WT[i] = (unsigned char)enc_fp8(256.f * W[(size_t)l * 641 * 128 + (size_t)k * 128 + n]);
}
__global__ __launch_bounds__(256) void k_tr_msg(const float* __restrict__ W,
                                                unsigned char* __restrict__ WT) {
    int i = blockIdx.x * 256 + threadIdx.x;
    if (i >= 3 * 256 * 384) return;
    int l = i / (256 * 384), r = i % (256 * 384);
    int n = r / 384, k = r % 384;
    WT[i] = (unsigned char)enc_fp8(256.f * W[(size_t)l * 384 * 256 + (size_t)k * 256 + n]);
}
__global__ __launch_bounds__(256) void k_tr_nu(const float* __restrict__ W,
                                               unsigned char* __restrict__ WT) {
    int i = blockIdx.x * 256 + threadIdx.x;
    if (i >= 3 * 256 * 512) return;
    int l = i / (256 * 512), r = i % (256 * 512);
    int n = r / 512, k = r % 512;
    WT[i] = (unsigned char)enc_fp8(256.f * W[(size_t)l * 512 * 256 + (size_t)k * 256 + n]);
}

// ---------- fp8 MFMA edge layer: 64 edges/block, 4 waves --------------------
// A = [he(0..127) | hn_src(128..383) | hn_dst(384..639)] fp8 in LDS
// edge GEMM 64x640x128 (+dist rank-1) -> he_new; msg GEMM 64x384x256 -> atomics
#define ELS 648  // A row stride (640 + 8)
#define HLS 136  // s_h row stride (128 + 8)

__global__ __launch_bounds__(256, 3) void k_edge_layer_fp8(
    const unsigned char* __restrict__ hn8, unsigned char* __restrict__ he8,
    const float* __restrict__ dist,
    const void* __restrict__ ei, const int* __restrict__ flag,
    const unsigned char* __restrict__ WTeu, const float* __restrict__ W_eu,
    const float* __restrict__ b_eu,
    const unsigned char* __restrict__ WTmsg, const float* __restrict__ b_msg,
    float* __restrict__ agg) {
    __shared__ unsigned char s_A[64 * ELS];  // 41472 B
    __shared__ unsigned char s_h[64 * HLS];  //  8704 B
    __shared__ float s_dist[64];
    __shared__ int s_dsti[64];
    int t = threadIdx.x;
    int eb = blockIdx.x * 64;
    int is64 = *flag;
    int row = t >> 2, sb = t & 3;

    if (t < 64) {
        s_dsti[t] = clampi(IDX(ei, (size_t)NE + eb + t, is64), NN);
        s_dist[t] = dist[eb + t];
    }
    // stage he (fp8 copy), k 0..127: 4 threads x 32B per row
    {
        const uint4* sp = (const uint4*)(he8 + (size_t)(eb + row) * 128 + sb * 32);
        uint4 a = sp[0], b = sp[1];
        *(uint4*)&s_A[row * ELS + sb * 32] = a;
        *(uint4*)&s_A[row * ELS + sb * 32 + 16] = b;
    }
    // stage hn[src] (fp8 copy), k 128..383: 4 threads x 64B per row
    {
        int id = clampi(IDX(ei, (size_t)eb + row, is64), NN);
        const uint4* sp = (const uint4*)(hn8 + (size_t)id * 256 + sb * 64);
        uint4 a = sp[0], b = sp[1], c = sp[2], d = sp[3];
        uint4* dp = (uint4*)&s_A[row * ELS + 128 + sb * 64];
        dp[0] = a; dp[1] = b; dp[2] = c; dp[3] = d;
    }
    // stage hn[dst], k 384..639
    {
        int id = clampi(IDX(ei, (size_t)NE + eb + row, is64), NN);
        const uint4* sp = (const uint4*)(hn8 + (size_t)id * 256 + sb * 64);
        uint4 a = sp[0], b = sp[1], c = sp[2], d = sp[3];
        uint4* dp = (uint4*)&s_A[row * ELS + 384 + sb * 64];
        dp[0] = a; dp[1] = b; dp[2] = c; dp[3] = d;
    }
    __syncthreads();

    int lane = t & 63, wv = t >> 6;
    int quad = lane >> 4, l16 = lane & 15;
    v4f zero4 = {0.f, 0.f, 0.f, 0.f};

    // ---- edge update GEMM: wave -> N-tiles {2w,2w+1}, M-tiles 0..3 ----
    v4f acc[4][2];
#pragma unroll
    for (int mt = 0; mt < 4; ++mt) { acc[mt][0] = zero4; acc[mt][1] = zero4; }
    int n0 = wv * 2;
    const unsigned char* B0 = WTeu + (size_t)(n0 * 16 + l16) * 640;
    const unsigned char* B1 = WTeu + (size_t)((n0 + 1) * 16 + l16) * 640;
#pragma unroll 4
    for (int k = 0; k < 640; k += 32) {
        int ko = k + quad * 8;
        ll64 b0 = *(const ll64*)(B0 + ko);
        ll64 b1 = *(const ll64*)(B1 + ko);
#pragma unroll
        for (int mt = 0; mt < 4; ++mt) {
            ll64 a = *(const ll64*)&s_A[(mt * 16 + l16) * ELS + ko];
            acc[mt][0] = MFMA8(a, b0, acc[mt][0]);
            acc[mt][1] = MFMA8(a, b1, acc[mt][1]);
        }
    }
    // edge epilogue: de-scale + dist*w640 + bias, relu -> s_h fp8 + he8 global
#pragma unroll
    for (int nl = 0; nl < 2; ++nl) {
        int c = (n0 + nl) * 16 + l16;
        float w640 = W_eu[640 * 128 + c];
        float bb = b_eu[c];
#pragma unroll
        for (int mt = 0; mt < 4; ++mt)
#pragma unroll
            for (int r = 0; r < 4; ++r) {
                int rw = mt * 16 + quad * 4 + r;
                float v = acc[mt][nl][r] * INV_S + s_dist[rw] * w640 + bb;
                v = fmaxf(v, 0.f);
                unsigned char q = (unsigned char)enc_fp8(ASCL * v);
                s_h[rw * HLS + c] = q;
                he8[(size_t)(eb + rw) * 128 + c] = q;
            }
    }
    __syncthreads();

    // ---- msg GEMM: wave -> N-tiles {4w..4w+3}, M-tiles 0..3; K=384 ----
    v4f mac[4][4];
#pragma unroll
    for (int mt = 0; mt < 4; ++mt)
#pragma unroll
        for (int nl = 0; nl < 4; ++nl) mac[mt][nl] = zero4;
    int q0 = wv * 4;
    const unsigned char* MB[4];
#pragma unroll
    for (int nl = 0; nl < 4; ++nl)
        MB[nl] = WTmsg + (size_t)((q0 + nl) * 16 + l16) * 384;
    // part A: hn_src (k 0..255 -> s_A offset 128)
#pragma unroll 2
    for (int k = 0; k < 256; k += 32) {
        int ko = k + quad * 8;
        ll64 b[4];
#pragma unroll
        for (int nl = 0; nl < 4; ++nl) b[nl] = *(const ll64*)(MB[nl] + ko);
#pragma unroll
        for (int mt = 0; mt < 4; ++mt) {
            ll64 a = *(const ll64*)&s_A[(mt * 16 + l16) * ELS + 128 + ko];
#pragma unroll
            for (int nl = 0; nl < 4; ++nl) mac[mt][nl] = MFMA8(a, b[nl], mac[mt][nl]);
        }
    }
    // part B: he_new (k 256..383 -> s_h)
#pragma unroll 2
    for (int k = 0; k < 128; k += 32) {
        int ko = k + quad * 8;
        ll64 b[4];
#pragma unroll
        for (int nl = 0; nl < 4; ++nl) b[nl] = *(const ll64*)(MB[nl] + 256 + ko);
#pragma unroll
        for (int mt = 0; mt < 4; ++mt) {
            ll64 a = *(const ll64*)&s_h[(mt * 16 + l16) * HLS + ko];
#pragma unroll
            for (int nl = 0; nl < 4; ++nl) mac[mt][nl] = MFMA8(a, b[nl], mac[mt][nl]);
        }
    }
    // msg epilogue: de-scale + bias + relu -> f32 scatter atomics
#pragma unroll
    for (int nl = 0; nl < 4; ++nl) {
        int c = (q0 + nl) * 16 + l16;
        float bm = b_msg[c];
#pragma unroll
        for (int mt = 0; mt < 4; ++mt)
#pragma unroll
            for (int r = 0; r < 4; ++r) {
                int rw = mt * 16 + quad * 4 + r;
                float v = fmaxf(mac[mt][nl][r] * INV_S + bm, 0.f);
                atomicAdd(&agg[(size_t)s_dsti[rw] * 256 + c], v);
            }
    }
}

// ---------- fp8 MFMA node layer: 32 nodes/block -----------------------------
#define NLS 528  // 512 + 16 pad

__global__ __launch_bounds__(256) void k_node_layer_fp8(
    unsigned char* __restrict__ hn8, const float* __restrict__ agg,
    const unsigned char* __restrict__ WTnu, const float* __restrict__ b) {
    __shared__ unsigned char s_A[32 * NLS];  // 16896 B
    int t = threadIdx.x;
    int rb = blockIdx.x * 32;
    int row = t >> 3, sb = t & 7;
    // stage hn fp8 copy (k 0..255): 8 threads x 32B per row
    {
        const uint4* sp = (const uint4*)(hn8 + (size_t)(rb + row) * 256 + sb * 32);
        uint4 a = sp[0], b2 = sp[1];
        *(uint4*)&s_A[row * NLS + sb * 32] = a;
        *(uint4*)&s_A[row * NLS + sb * 32 + 16] = b2;
    }
    // stage agg f32 -> fp8 x16 (k 256..511): 32 floats per thread
    {
        const float* sp = agg + (size_t)(rb + row) * 256 + sb * 32;
        union { unsigned char b[32]; uint4 q[2]; } u;
#pragma unroll
        for (int j = 0; j < 32; ++j) u.b[j] = (unsigned char)enc_fp8(ASCL * sp[j]);
        uint4* dp = (uint4*)&s_A[row * NLS + 256 + sb * 32];
        dp[0] = u.q[0]; dp[1] = u.q[1];
    }
    __syncthreads();
    int lane = t & 63, wv = t >> 6, quad = lane >> 4, l16 = lane & 15;
    v4f zero4 = {0.f, 0.f, 0.f, 0.f};
    v4f acc[2][4];
#pragma unroll
    for (int nl = 0; nl < 4; ++nl) { acc[0][nl] = zero4; acc[1][nl] = zero4; }
    int q0 = wv * 4;
    const unsigned char* MB[4];
#pragma unroll
    for (int nl = 0; nl < 4; ++nl)
        MB[nl] = WTnu + (size_t)((q0 + nl) * 16 + l16) * 512;
#pragma unroll 2
    for (int k = 0; k < 512; k += 32) {
        int ko = k + quad * 8;
        ll64 a0 = *(const ll64*)&s_A[l16 * NLS + ko];
        ll64 a1 = *(const ll64*)&s_A[(16 + l16) * NLS + ko];
#pragma unroll
        for (int nl = 0; nl < 4; ++nl) {
            ll64 bb = *(const ll64*)(MB[nl] + ko);
            acc[0][nl] = MFMA8(a0, bb, acc[0][nl]);
            acc[1][nl] = MFMA8(a1, bb, acc[1][nl]);
        }
    }
#pragma unroll
    for (int nl = 0; nl < 4; ++nl) {
        int c = (q0 + nl) * 16 + l16;
        float bv = b[c];
#pragma unroll
        for (int mt = 0; mt < 2; ++mt)
#pragma unroll
            for (int r = 0; r < 4; ++r) {
                int rw = mt * 16 + quad * 4 + r;
                float old = dec_fp8(s_A[rw * NLS + c]) * AINV;
                float v = old + fmaxf(acc[mt][nl][r] * INV_S + bv, 0.f);
                hn8[(size_t)(rb + rw) * 256 + c] = (unsigned char)enc_fp8(ASCL * v);
            }
    }
}

// ---------- pooling + final MLP --------------------------------------------
__device__ __forceinline__ int lbound(const void* a, int n, int v, int is64) {
    int lo = 0, hi = n;
    while (lo < hi) {
        int mid = (lo + hi) >> 1;
        if (IDX(a, mid, is64) < v) lo = mid + 1; else hi = mid;
    }
    return lo;
}

__global__ __launch_bounds__(512) void k_pool_mlp(
    const unsigned char* __restrict__ hn8, const unsigned char* __restrict__ he8,
    const void* __restrict__ bn, const void* __restrict__ be,
    const int* __restrict__ flag,
    const float* __restrict__ Wf1, const float* __restrict__ bf1,
    const float* __restrict__ Wf2, const float* __restrict__ bf2,
    float* __restrict__ out) {
    __shared__ float s_sub[384];
    __shared__ float s_hid[512];
    int b = blockIdx.x;
    int t = threadIdx.x;
    int is64 = *flag;
    if (t < 256) {
        int lo = lbound(bn, NN, b, is64), hi = lbound(bn, NN, b + 1, is64);
        float s = 0.f;
        for (int i = lo; i < hi; ++i) s += dec_fp8(hn8[(size_t)i * 256 + t]);
        s_sub[t] = s * AINV / fmaxf((float)(hi - lo), 1.f);
    } else if (t < 384) {
        int c = t - 256;
        int lo = lbound(be, NE, b, is64), hi = lbound(be, NE, b + 1, is64);
        float s = 0.f;
        for (int i = lo; i < hi; ++i) s += dec_fp8(he8[(size_t)i * 128 + c]);
        s_sub[256 + c] = s * AINV / fmaxf((float)(hi - lo), 1.f);
    }
    __syncthreads();
    float hacc = bf1[t];
    for (int k = 0; k < 384; ++k) hacc += s_sub[k] * Wf1[k * 512 + t];
    s_hid[t] = fmaxf(hacc, 0.f);
    __syncthreads();
    if (t < 256) {
        float o = bf2[t];
        for (int k = 0; k < 512; ++k) o += s_hid[k] * Wf2[k * 256 + t];
        out[(size_t)b * 256 + t] = o;
    }
}

// ---------- second output ---------------------------------------------------
__global__ __launch_bounds__(256) void k_write_batch(const void* __restrict__ bn,
                                                     const int* __restrict__ flag,
                                                     float* __restrict__ out) {
    int i = blockIdx.x * 256 + threadIdx.x;
    if (i < NN) out[(size_t)NB * 256 + i] = (float)IDX(bn, i, *flag);
}

__global__ __launch_bounds__(256) void k_fill(float* __restrict__ p, int n, float v) {
    int i = blockIdx.x * 256 + threadIdx.x;
    if (i < n) p[i] = v;
}

extern "C" void kernel_launch(void* const* d_in, const int* in_sizes, int n_in,
                              void* d_out, int out_size, void* d_ws, size_t ws_size,
                              hipStream_t stream) {
    const float* h_node = (const float*)d_in[0];
    const float* pos    = (const float*)d_in[1];
    const float* h_edge = (const float*)d_in[2];
    const float* W_node = (const float*)d_in[3];
    const float* W_edge = (const float*)d_in[4];
    const float* W_eu   = (const float*)d_in[5];
    const float* b_eu   = (const float*)d_in[6];
    const float* W_msg  = (const float*)d_in[7];
    const float* b_msg  = (const float*)d_in[8];
    const float* W_nu   = (const float*)d_in[9];
    const float* b_nu   = (const float*)d_in[10];
    const float* Wf1    = (const float*)d_in[11];
    const float* bf1    = (const float*)d_in[12];
    const float* Wf2    = (const float*)d_in[13];
    const float* bf2    = (const float*)d_in[14];
    const void* ei = d_in[15];
    const void* bn = d_in[16];
    const void* be = d_in[17];

    float* out = (float*)d_out;

    const size_t SZ_FLAG  = 256;
    const size_t SZ_HN    = (size_t)NN * 256;       //  25.6  MB (fp8)
    const size_t SZ_HE    = (size_t)NE * 128;       //  81.92 MB (fp8)
    const size_t SZ_AGG   = (size_t)NN * 256 * 4;   // 102.4  MB (f32)
    const size_t SZ_DIST  = (size_t)NE * 4;         //   2.56 MB
    const size_t SZ_WTEU  = (size_t)3 * 128 * 640;
    const size_t SZ_WTMSG = (size_t)3 * 256 * 384;
    const size_t SZ_WTNU  = (size_t)3 * 256 * 512;
    const size_t NEED = SZ_FLAG + SZ_HN + SZ_HE + SZ_AGG + SZ_DIST +
                        SZ_WTEU + SZ_WTMSG + SZ_WTNU;  // ~213.5 MB

    char* ws = (char*)d_ws;
    int* flag = (int*)ws;                       ws += SZ_FLAG;
    unsigned char* hn8 = (unsigned char*)ws;    ws += SZ_HN;
    unsigned char* he8 = (unsigned char*)ws;    ws += SZ_HE;
    float* agg = (float*)ws;                    ws += SZ_AGG;
    float* dist = (float*)ws;                   ws += SZ_DIST;
    unsigned char* WTeu = (unsigned char*)ws;   ws += SZ_WTEU;
    unsigned char* WTmsg = (unsigned char*)ws;  ws += SZ_WTMSG;
    unsigned char* WTnu = (unsigned char*)ws;   ws += SZ_WTNU;

    if (ws_size < NEED) {
        float enc = -(100000.0f + (float)(ws_size >> 20));
        k_detect<<<1, 64, 0, stream>>>((const int*)bn, flag);
        k_fill<<<(NB * 256 + 255) / 256, 256, 0, stream>>>(out, NB * 256, enc);
        k_write_batch<<<(NN + 255) / 256, 256, 0, stream>>>(bn, flag, out);
        return;
    }

    k_detect<<<1, 64, 0, stream>>>((const int*)bn, flag);
    k_tr_eu<<<(3 * 128 * 640 + 255) / 256, 256, 0, stream>>>(W_eu, WTeu);
    k_tr_msg<<<(3 * 256 * 384 + 255) / 256, 256, 0, stream>>>(W_msg, WTmsg);
    k_tr_nu<<<(3 * 256 * 512 + 255) / 256, 256, 0, stream>>>(W_nu, WTnu);
    k_node_embed<<<NN / 8, 256, 0, stream>>>(h_node, W_node, hn8);
    k_edge_embed<<<NE / 16, 256, 0, stream>>>(h_edge, W_edge, he8);
    k_dist<<<(NE + 255) / 256, 256, 0, stream>>>(pos, ei, flag, dist);

    for (int l = 0; l < 3; ++l) {
        hipMemsetAsync(agg, 0, SZ_AGG, stream);
        k_edge_layer_fp8<<<NE / 64, 256, 0, stream>>>(
            hn8, he8, dist, ei, flag,
            WTeu + (size_t)l * 128 * 640, W_eu + (size_t)l * 641 * 128,
            b_eu + (size_t)l * 128,
            WTmsg + (size_t)l * 256 * 384, b_msg + (size_t)l * 256, agg);
        k_node_layer_fp8<<<NN / 32, 256, 0, stream>>>(
            hn8, agg, WTnu + (size_t)l * 256 * 512, b_nu + (size_t)l * 256);
    }

    k_pool_mlp<<<NB, 512, 0, stream>>>(hn8, he8, bn, be, flag,
                                       Wf1, bf1, Wf2, bf2, out);
    k_write_batch<<<(NN + 255) / 256, 256, 0, stream>>>(bn, flag, out);
}